// Round 14
// baseline (47.910 us; speedup 1.0000x reference)
//
#include <hip/hip_runtime.h>
#include <math.h>

// TopKGate: logits = x @ W^T ; softmax ; top-2 ; scatter weights + indices(float).
// x: [8192,4096] f32, W: [64,4096] f32.
// d_out (f32 flat): weights [8192*64] then indices [8192*2] as floats.
//
// MFMA path: f32 as bf16 hi/lo split, 3 passes (hh+lh+hl; ll ~2^-16 dropped).
// Round-14: 32x32x16 MFMA, 32 tokens/wave (M=32, N=64 = 2 tiles). Same 8
// ds_read_b128 per chunk per wave as round-13 but feeding 2x the tokens ->
// per-token LDS cost halves. Block = 8 waves x 32 tok = 256 tokens; grid =
// 32 tg x 8 ks = 256 blocks = exactly 1/CU, ONE round (round-13 ran two).
// B k-panel (512 k = 128 KB) in LDS, staged once, one barrier total; x is
// the only vmem stream (ring depth 3 chunks). Partials + KS=8 finalize.

#define TOKENS 8192
#define DIM    4096
#define NEXP   64
#define NCHW   (DIM / 32)                    // 128 global k-chunks
#define FRAGS  ((size_t)NCHW * 4 * 64 * 8)   // 262144 shorts per array

#define KS     8                             // k-split across blocks
#define KSEG   (DIM / KS)                    // 512 k per block
#define NCH    (KSEG / 32)                   // 16 chunks per block

#define SBAR() __builtin_amdgcn_sched_barrier(0)

typedef __attribute__((ext_vector_type(8)))  short short8;
typedef __attribute__((ext_vector_type(8)))  float f32x8;
typedef __attribute__((ext_vector_type(16))) float f32x16;

__device__ __forceinline__ void bf16split(float v, short& hi, short& lo) {
    unsigned u = __float_as_uint(v);
    hi = (short)(u >> 16);
    float r = v - __uint_as_float(u & 0xffff0000u);
    lo = (short)(__float_as_uint(r) >> 16);
}

// ---- prep: W[64][4096] -> 32x32-fragment-ordered bf16 hi/lo ----
// frag f = ks2*2+nt (ks2: k-step in chunk, nt: 32-expert tile).
// Whf[((c*4+f)*64+lane)*8 + j] = bf16hi(W[nt*32+(lane&31)][k]),
// k = c*32 + ks2*16 + (lane>>5)*8 + j.  (same k-map as A: consistency trick)
__global__ void tg_prepw(const float* __restrict__ W,
                         short* __restrict__ Whf, short* __restrict__ Wlf) {
    int gid  = blockIdx.x * 256 + threadIdx.x;   // 32768 threads
    int c    = gid >> 8, rem = gid & 255;
    int f    = rem >> 6, lane = rem & 63;
    int ks2  = f >> 1, nt = f & 1;
    int e    = nt * 32 + (lane & 31);
    int kb   = c * 32 + ks2 * 16 + (lane >> 5) * 8;
    const float* wp = W + (size_t)e * DIM + kb;
    short8 h, l;
#pragma unroll
    for (int j = 0; j < 8; ++j) {
        short hh, ll;
        bf16split(wp[j], hh, ll);
        h[j] = hh; l[j] = ll;
    }
    size_t o = ((size_t)(c * 4 + f) * 64 + lane) * 8;
    *reinterpret_cast<short8*>(Whf + o) = h;
    *reinterpret_cast<short8*>(Wlf + o) = l;
}

// ---- main: 256 tokens/block (8 waves x 32), shared B panel in LDS ----
__global__ __launch_bounds__(512, 2)
void tg_mfma(const float* __restrict__ x,
             const short* __restrict__ Whf, const short* __restrict__ Wlf,
             float* __restrict__ part) {
    // B panel: [hi/lo][chunk][frag][lane] short8 = 128 KB
    __shared__ short8 Bls[2][NCH][4][64];

    const int tid  = threadIdx.x;
    const int lane = tid & 63;
    const int wave = tid >> 6;                   // token sub-group 0..7
    const int tg   = blockIdx.x >> 3;            // token group 0..31
    const int ks   = blockIdx.x & 7;             // k split 0..7
    const int t0   = tg * 256 + wave * 32;
    const int r32  = lane & 31;                  // A row / B,D col (within tile)
    const int grp  = lane >> 5;                  // k-half group

    // ---- stage B panel: flat 2 x 64 KB copy, 16 x 16B per thread ----
    {
        const short8* srch = reinterpret_cast<const short8*>(Whf) + (size_t)ks * (NCH * 4 * 64);
        const short8* srcl = reinterpret_cast<const short8*>(Wlf) + (size_t)ks * (NCH * 4 * 64);
        short8* d0 = &Bls[0][0][0][0];
        short8* d1 = &Bls[1][0][0][0];
#pragma unroll
        for (int i = 0; i < 8; ++i) {
            d0[i * 512 + tid] = srch[i * 512 + tid];
            d1[i * 512 + tid] = srcl[i * 512 + tid];
        }
    }
    __syncthreads();   // the only barrier in the kernel

    const float* xp = x + (size_t)(t0 + r32) * DIM + ks * KSEG + grp * 8;

    f32x16 acc0 = {0,0,0,0,0,0,0,0,0,0,0,0,0,0,0,0};
    f32x16 acc1 = {0,0,0,0,0,0,0,0,0,0,0,0,0,0,0,0};

    short8 bA[8], bB[8];
    auto dsB = [&](short8 (&b)[8], int c) {      // 8 x ds_read_b128, conflict-free
#pragma unroll
        for (int f = 0; f < 4; ++f) {
            b[f]     = Bls[0][c][f][lane];
            b[4 + f] = Bls[1][c][f][lane];
        }
    };
    auto ldx = [&](int c, int h) {
        return *reinterpret_cast<const f32x8*>(xp + c * 32 + h * 16);
    };
    auto cvt = [&](const f32x8& xv, short8& ah, short8& al) {
#pragma unroll
        for (int j = 0; j < 8; ++j) {
            short hh, ll;
            bf16split(xv[j], hh, ll);
            ah[j] = hh; al[j] = ll;
        }
    };
    // 3-pass split: hh + lh + hl (ll ~ 2^-16 relative, dropped)
    auto mfma12 = [&](const short8& ah0, const short8& al0,
                      const short8& ah1, const short8& al1, const short8 (&b)[8]) {
        acc0 = __builtin_amdgcn_mfma_f32_32x32x16_bf16(ah0, b[0], acc0, 0, 0, 0);
        acc1 = __builtin_amdgcn_mfma_f32_32x32x16_bf16(ah0, b[1], acc1, 0, 0, 0);
        acc0 = __builtin_amdgcn_mfma_f32_32x32x16_bf16(ah1, b[2], acc0, 0, 0, 0);
        acc1 = __builtin_amdgcn_mfma_f32_32x32x16_bf16(ah1, b[3], acc1, 0, 0, 0);
        acc0 = __builtin_amdgcn_mfma_f32_32x32x16_bf16(al0, b[0], acc0, 0, 0, 0);
        acc1 = __builtin_amdgcn_mfma_f32_32x32x16_bf16(al0, b[1], acc1, 0, 0, 0);
        acc0 = __builtin_amdgcn_mfma_f32_32x32x16_bf16(al1, b[2], acc0, 0, 0, 0);
        acc1 = __builtin_amdgcn_mfma_f32_32x32x16_bf16(al1, b[3], acc1, 0, 0, 0);
        acc0 = __builtin_amdgcn_mfma_f32_32x32x16_bf16(ah0, b[4], acc0, 0, 0, 0);
        acc1 = __builtin_amdgcn_mfma_f32_32x32x16_bf16(ah0, b[5], acc1, 0, 0, 0);
        acc0 = __builtin_amdgcn_mfma_f32_32x32x16_bf16(ah1, b[6], acc0, 0, 0, 0);
        acc1 = __builtin_amdgcn_mfma_f32_32x32x16_bf16(ah1, b[7], acc1, 0, 0, 0);
    };

    // prologue: B(0) from LDS, x ring depth 3 chunks in flight
    f32x8 xA0 = ldx(0, 0), xA1 = ldx(0, 1);
    f32x8 xB0 = ldx(1, 0), xB1 = ldx(1, 1);
    f32x8 xC0 = ldx(2, 0), xC1 = ldx(2, 1);
    dsB(bA, 0);
    SBAR();

    short8 ah0, al0, ah1, al1;
#define PH(c, XV0, XV1, BC, BN)                                      \
    {                                                                \
        cvt(XV0, ah0, al0); cvt(XV1, ah1, al1);                      \
        SBAR();                                                      \
        if ((c) + 1 < NCH) dsB(BN, (c) + 1);                         \
        if ((c) + 3 < NCH) { XV0 = ldx((c) + 3, 0); XV1 = ldx((c) + 3, 1); } \
        SBAR();                                                      \
        mfma12(ah0, al0, ah1, al1, BC);                              \
        SBAR();                                                      \
    }

    PH(0,  xA0, xA1, bA, bB)
    PH(1,  xB0, xB1, bB, bA)
    PH(2,  xC0, xC1, bA, bB)
    PH(3,  xA0, xA1, bB, bA)
    PH(4,  xB0, xB1, bA, bB)
    PH(5,  xC0, xC1, bB, bA)
    PH(6,  xA0, xA1, bA, bB)
    PH(7,  xB0, xB1, bB, bA)
    PH(8,  xC0, xC1, bA, bB)
    PH(9,  xA0, xA1, bB, bA)
    PH(10, xB0, xB1, bA, bB)
    PH(11, xC0, xC1, bB, bA)
    PH(12, xA0, xA1, bA, bB)
    PH(13, xB0, xB1, bB, bA)
    PH(14, xC0, xC1, bA, bB)
    PH(15, xA0, xA1, bB, bA)
#undef PH

    // ---- direct partial write; D layout (m74/m101-verified):
    // col = lane&31, row = (reg&3) + 8*(reg>>2) + 4*(lane>>5)
    float* pp = part + ((size_t)ks * TOKENS + t0) * NEXP;
#pragma unroll
    for (int r = 0; r < 16; ++r) {
        const int rr = (r & 3) + 8 * (r >> 2) + 4 * grp;
        pp[rr * NEXP + r32]      = acc0[r];
        pp[rr * NEXP + 32 + r32] = acc1[r];
    }
}

// ---- finalize: sum 8 k-split partials, wave-per-token softmax + top-2 ----
__global__ __launch_bounds__(256)
void tg_final(const float* __restrict__ part,
              float* __restrict__ out_w, float* __restrict__ out_i) {
    const int lane = threadIdx.x & 63;
    const int wv   = threadIdx.x >> 6;
    const int t    = blockIdx.x * 4 + wv;        // one token per wave

    float s = 0.0f;
#pragma unroll
    for (int k = 0; k < KS; ++k)                 // coalesced 256-B reads
        s += part[((size_t)k * TOKENS + t) * NEXP + lane];

    // softmax over 64 lanes (butterfly: all lanes converge bit-identically)
    float m = s;
#pragma unroll
    for (int o = 32; o > 0; o >>= 1) m = fmaxf(m, __shfl_xor(m, o));
    float p = expf(s - m);
    float sum = p;
#pragma unroll
    for (int o = 32; o > 0; o >>= 1) sum += __shfl_xor(sum, o);
    const float prob = p / sum;

    // top-1: max value, tie -> lower index (jax top_k order)
    float v1 = prob; int i1 = lane;
#pragma unroll
    for (int o = 32; o > 0; o >>= 1) {
        float ov = __shfl_xor(v1, o); int oi = __shfl_xor(i1, o);
        if (ov > v1 || (ov == v1 && oi < i1)) { v1 = ov; i1 = oi; }
    }
    // top-2: mask winner (probs >= 0 > -1)
    float v2 = (lane == i1) ? -1.0f : prob; int i2 = lane;
#pragma unroll
    for (int o = 32; o > 0; o >>= 1) {
        float ov = __shfl_xor(v2, o); int oi = __shfl_xor(i2, o);
        if (ov > v2 || (ov == v2 && oi < i2)) { v2 = ov; i2 = oi; }
    }

    out_w[(size_t)t * NEXP + lane] = (lane == i1) ? v1 : (lane == i2) ? v2 : 0.0f;
    if (lane == 0) {
        out_i[(size_t)t * 2 + 0] = (float)i1;
        out_i[(size_t)t * 2 + 1] = (float)i2;
    }
}

extern "C" void kernel_launch(void* const* d_in, const int* in_sizes, int n_in,
                              void* d_out, int out_size, void* d_ws, size_t ws_size,
                              hipStream_t stream) {
    const float* x = (const float*)d_in[0];
    const float* W = (const float*)d_in[1];
    float* out_w = (float*)d_out;
    float* out_i = out_w + (size_t)TOKENS * NEXP;

    float* part = (float*)d_ws;                              // 8*8192*64*4 = 16 MB
    short* Whf  = (short*)((char*)d_ws + (size_t)KS * TOKENS * NEXP * 4);
    short* Wlf  = Whf + FRAGS;

    tg_prepw<<<dim3(128), dim3(256), 0, stream>>>(W, Whf, Wlf);
    tg_mfma <<<dim3((TOKENS / 256) * KS), dim3(512), 0, stream>>>(x, Whf, Wlf, part);
    tg_final<<<dim3(TOKENS / 4), dim3(256), 0, stream>>>(part, out_w, out_i);
}